// Round 10
// baseline (267.522 us; speedup 1.0000x reference)
//
#include <hip/hip_runtime.h>
#include <hip/hip_bf16.h>
#include <math.h>

typedef __bf16 bf16;
typedef __attribute__((ext_vector_type(8))) __bf16 bf16x8;
typedef __attribute__((ext_vector_type(4))) __bf16 bf16x4;
typedef __attribute__((ext_vector_type(4))) float floatx4;
typedef __attribute__((ext_vector_type(16))) float floatx16;

#define BB 2
#define NN 2048
#define LL 2048
#define DD 1024
#define HH 16
#define HDD 64

// Q pre-scale: HD^-0.5 * log2(e) -> scores in log2 units
#define QSCALE (0.125f * 1.44269504f)
#define PCLAMP 21.66f
#define MBIAS  (-100000.0f)

// async global->LDS, 16B per lane. LDS dest must be wave-uniform + lane*16.
__device__ __forceinline__ void async16(const bf16* g, bf16* l) {
  __builtin_amdgcn_global_load_lds((const __attribute__((address_space(1))) void*)(g),
                                   (__attribute__((address_space(3))) void*)(l), 16, 0, 0);
}

// ---------------------------------------------------------------------------
// Fused prep: [0,nconv) f32->bf16 converts (two inputs, nconv/2 blocks each),
// [nconv, nconv+1024) W-transpose tiles (4 matrices), [nconv+1024] mask ->
// biasF[2][2048] floats (dtype auto-detect: int32 {0,1} / bytes / f32 {0,1}).
// ---------------------------------------------------------------------------
__global__ __launch_bounds__(256) void prep_kernel(
    const float* __restrict__ xq, const float* __restrict__ xkv,
    bf16* __restrict__ Xqb, bf16* __restrict__ Xkvb, int nconv, int elemsEach,
    const float* __restrict__ W0, const float* __restrict__ W1,
    const float* __restrict__ W2, const float* __restrict__ W3,
    bf16* __restrict__ T0, bf16* __restrict__ T1,
    bf16* __restrict__ T2, bf16* __restrict__ T3,
    const unsigned* __restrict__ mask, float* __restrict__ biasF)
{
  __shared__ bf16 Tb[64][72];
  const int bid = blockIdx.x;
  const int t = threadIdx.x;

  if (bid < nconv) {
    const int half = nconv >> 1;
    const float* s = (bid < half) ? xq : xkv;
    bf16* d = (bid < half) ? Xqb : Xkvb;
    int gid = (bid < half) ? bid : bid - half;
    int idx = (gid * 256 + t) * 8;
    if (idx >= elemsEach) return;
    floatx4 a = *(const floatx4*)&s[idx];
    floatx4 b = *(const floatx4*)&s[idx + 4];
    bf16x8 o;
#pragma unroll
    for (int e = 0; e < 4; e++) { o[e] = (bf16)a[e]; o[4 + e] = (bf16)b[e]; }
    *(bf16x8*)&d[idx] = o;
    return;
  }
  if (bid < nconv + 1024) {
    const int wb = bid - nconv;
    const int which = wb >> 8;
    const float* W = which == 0 ? W0 : which == 1 ? W1 : which == 2 ? W2 : W3;
    bf16*       T = which == 0 ? T0 : which == 1 ? T1 : which == 2 ? T2 : T3;
    const int tile = wb & 255;
    const int k0 = (tile >> 4) * 64, n0 = (tile & 15) * 64;
    const int r = t >> 2;
    const int c = (t & 3) * 16;
    const float* Wr = W + (size_t)(k0 + r) * 1024 + n0 + c;
    floatx4 f0 = *(const floatx4*)(Wr + 0);
    floatx4 f1 = *(const floatx4*)(Wr + 4);
    floatx4 f2 = *(const floatx4*)(Wr + 8);
    floatx4 f3 = *(const floatx4*)(Wr + 12);
#pragma unroll
    for (int e = 0; e < 4; e++) {
      Tb[c + e][r]      = (bf16)f0[e];
      Tb[c + 4 + e][r]  = (bf16)f1[e];
      Tb[c + 8 + e][r]  = (bf16)f2[e];
      Tb[c + 12 + e][r] = (bf16)f3[e];
    }
    __syncthreads();
    bf16* Tr = T + (size_t)(n0 + r) * 1024 + k0 + c;
    *(bf16x8*)&Tr[0] = *(const bf16x8*)&Tb[r][c];
    *(bf16x8*)&Tr[8] = *(const bf16x8*)&Tb[r][c + 8];
    return;
  }
  // mask -> biasF (one block)
  __shared__ int hasBig, hasFloat;
  if (t == 0) { hasBig = 0; hasFloat = 0; }
  __syncthreads();
  int big = 0, flt = 0;
  for (int idx = t; idx < 1024; idx += 256) {
    unsigned v = mask[idx];
    if (v == 0x3F800000u) flt = 1;
    else if (v > 1u) big = 1;
  }
  if (big) atomicOr(&hasBig, 1);
  if (flt) atomicOr(&hasFloat, 1);
  __syncthreads();
  const int mode = hasFloat ? 2 : (hasBig ? 1 : 0);
  for (int k = t * 16; k < t * 16 + 16; k++) {
    bool m;
    if (mode == 0)      m = ((const int*)mask)[k] != 0;
    else if (mode == 1) m = ((const unsigned char*)mask)[k] != 0;
    else                m = ((const float*)mask)[k] != 0.0f;
    biasF[k] = m ? MBIAS : 0.0f;
  }
}

// ---------------------------------------------------------------------------
// qkv GEMM body: 128x128 tile, BK=64, 32x32x16 MFMAs (half the LDS fragment
// bytes per MAC vs 16x16x32). 4 waves 2x2; wave = 64x64 = 2x2 tiles x 4
// k-steps = 16 MFMAs/BK. Staging via global_load_lds dwordx4.
// transv: write bf16 V^T globally as Vt[b][col][key].
// ---------------------------------------------------------------------------
template <typename TC>
__device__ __forceinline__ void gemm_body32(
    int bx, const bf16* __restrict__ A, const bf16* __restrict__ Wt,
    const float* __restrict__ bias, TC* __restrict__ C, float scale, int transv)
{
  __shared__ bf16 As[128 * 64];
  __shared__ bf16 Bs[128 * 64];

  const int tm = bx >> 3, tn = bx & 7;
  const int m0 = tm * 128, n0 = tn * 128;
  const int t = threadIdx.x;
  const int w = t >> 6, l = t & 63;
  const int col = l & 31, half = l >> 5;
  const int wm = (w >> 1) * 64, wn = (w & 1) * 64;
  const int sr = t >> 3;
  const int sc = (t & 7) * 8;

  floatx16 acc[2][2];
#pragma unroll
  for (int mi = 0; mi < 2; mi++)
#pragma unroll
    for (int ni = 0; ni < 2; ni++)
#pragma unroll
      for (int e = 0; e < 16; e++) acc[mi][ni][e] = 0.0f;

  for (int k0 = 0; k0 < 1024; k0 += 64) {
    __syncthreads();
#pragma unroll
    for (int j = 0; j < 4; j++)
      async16(&A[(size_t)(m0 + j * 32 + sr) * 1024 + k0 + sc], &As[(j * 32 + sr) * 64 + sc]);
#pragma unroll
    for (int j = 0; j < 4; j++)
      async16(&Wt[(size_t)(n0 + j * 32 + sr) * 1024 + k0 + sc], &Bs[(j * 32 + sr) * 64 + sc]);
    __syncthreads();
#pragma unroll
    for (int kk = 0; kk < 4; kk++) {
      bf16x8 af[2], bfr[2];
#pragma unroll
      for (int mi = 0; mi < 2; mi++)
        af[mi] = *(const bf16x8*)&As[(wm + mi * 32 + col) * 64 + kk * 16 + half * 8];
#pragma unroll
      for (int ni = 0; ni < 2; ni++)
        bfr[ni] = *(const bf16x8*)&Bs[(wn + ni * 32 + col) * 64 + kk * 16 + half * 8];
#pragma unroll
      for (int mi = 0; mi < 2; mi++)
#pragma unroll
        for (int ni = 0; ni < 2; ni++)
          acc[mi][ni] = __builtin_amdgcn_mfma_f32_32x32x16_bf16(af[mi], bfr[ni], acc[mi][ni], 0, 0, 0);
    }
  }
  // 32x32 C/D layout: col = lane&31, row = (reg&3) + 8*(reg>>2) + 4*(lane>>5)
#pragma unroll
  for (int ni = 0; ni < 2; ni++) {
    int colg = n0 + wn + ni * 32 + col;
    float bv = bias[colg];
#pragma unroll
    for (int mi = 0; mi < 2; mi++) {
      int rbase = m0 + wm + mi * 32 + half * 4;
      if (transv) {
#pragma unroll
        for (int g = 0; g < 4; g++) {
          int key0 = rbase + g * 8;
          int bb = key0 >> 11, key = key0 & 2047;
          bf16x4 v4;
#pragma unroll
          for (int r = 0; r < 4; r++) v4[r] = (bf16)(acc[mi][ni][g * 4 + r] + bv);
          *(bf16x4*)&((bf16*)C)[(size_t)bb * (DD * (size_t)LL) + (size_t)colg * LL + key] = v4;
        }
      } else {
#pragma unroll
        for (int g = 0; g < 4; g++)
#pragma unroll
          for (int r = 0; r < 4; r++)
            C[(size_t)(rbase + g * 8 + r) * 1024 + colg] = (TC)((acc[mi][ni][g * 4 + r] + bv) * scale);
      }
    }
  }
}

// Fused Q/K/V projection: grid = 3 << shift; which = bid >> shift.
__global__ __launch_bounds__(256) void qkv_gemm32(
    const bf16* __restrict__ Xq, const bf16* __restrict__ Xkv,
    const bf16* __restrict__ Wtq, const bf16* __restrict__ Wtk, const bf16* __restrict__ Wtv,
    const float* __restrict__ bq, const float* __restrict__ bk, const float* __restrict__ bv,
    bf16* __restrict__ Qp, bf16* __restrict__ Kp, bf16* __restrict__ VtG, int shift)
{
  const int bid = blockIdx.x;
  const int which = bid >> shift;
  const int bx = bid & ((1 << shift) - 1);
  if (which == 0)      gemm_body32<bf16>(bx, Xq,  Wtq, bq, Qp,  QSCALE, 0);
  else if (which == 1) gemm_body32<bf16>(bx, Xkv, Wtk, bk, Kp,  1.0f,   0);
  else                 gemm_body32<bf16>(bx, Xkv, Wtv, bv, VtG, 1.0f,   1);
}

// ---------------------------------------------------------------------------
// out GEMM (round-7/9 proven): 128x64 tile, BK=64, 16x16x32 MFMAs.
// ---------------------------------------------------------------------------
__global__ __launch_bounds__(256) void out_gemm(
    const bf16* __restrict__ A, const bf16* __restrict__ Wt,
    const float* __restrict__ bias, float* __restrict__ C)
{
  __shared__ bf16 As[128 * 64];
  __shared__ bf16 Bs[64 * 64];

  const int bx = blockIdx.x;
  const int tm = bx >> 4, tn = bx & 15;
  const int m0 = tm * 128, n0 = tn * 64;
  const int t = threadIdx.x;
  const int w = t >> 6, l = t & 63;
  const int q = l >> 4, i = l & 15;
  const int wm = (w >> 1) * 64, wn = (w & 1) * 32;
  const int sr = t >> 3;
  const int sc = (t & 7) * 8;

  const floatx4 zero = {0.f, 0.f, 0.f, 0.f};
  floatx4 acc[4][2];
#pragma unroll
  for (int mi = 0; mi < 4; mi++)
#pragma unroll
    for (int ni = 0; ni < 2; ni++) acc[mi][ni] = zero;

  for (int k0 = 0; k0 < 1024; k0 += 64) {
    __syncthreads();
#pragma unroll
    for (int j = 0; j < 4; j++)
      async16(&A[(size_t)(m0 + j * 32 + sr) * 1024 + k0 + sc], &As[(j * 32 + sr) * 64 + sc]);
#pragma unroll
    for (int j = 0; j < 2; j++)
      async16(&Wt[(size_t)(n0 + j * 32 + sr) * 1024 + k0 + sc], &Bs[(j * 32 + sr) * 64 + sc]);
    __syncthreads();
#pragma unroll
    for (int ks = 0; ks < 2; ks++) {
      bf16x8 af[4], bfr[2];
#pragma unroll
      for (int mi = 0; mi < 4; mi++)
        af[mi] = *(const bf16x8*)&As[(wm + mi * 16 + i) * 64 + ks * 32 + q * 8];
#pragma unroll
      for (int ni = 0; ni < 2; ni++)
        bfr[ni] = *(const bf16x8*)&Bs[(wn + ni * 16 + i) * 64 + ks * 32 + q * 8];
#pragma unroll
      for (int mi = 0; mi < 4; mi++)
#pragma unroll
        for (int ni = 0; ni < 2; ni++)
          acc[mi][ni] = __builtin_amdgcn_mfma_f32_16x16x32_bf16(af[mi], bfr[ni], acc[mi][ni], 0, 0, 0);
    }
  }
#pragma unroll
  for (int ni = 0; ni < 2; ni++) {
    int col = n0 + wn + ni * 16 + i;
    float bv = bias[col];
#pragma unroll
    for (int mi = 0; mi < 4; mi++) {
      int row = m0 + wm + mi * 16 + q * 4;
#pragma unroll
      for (int r = 0; r < 4; r++)
        C[(size_t)(row + r) * 1024 + col] = acc[mi][ni][r] + bv;
    }
  }
}

// ---------------------------------------------------------------------------
// Flash attention v5 = round-9 v4 with mask bias moved off the DS pipe:
// biasF floats come from global (L2-resident, register double-buffered like
// K/V). Block = 64 qrows, 4 waves x 16 qrows; XCD swizzle; S^T formulation;
// fixed-max softmax in log2 units.
// ---------------------------------------------------------------------------
__global__ __launch_bounds__(256) void attn_kernel(
    const bf16* __restrict__ Q, const bf16* __restrict__ K,
    const bf16* __restrict__ Vt, const float* __restrict__ biasF,
    bf16* __restrict__ O, int hbits)
{
  __shared__ bf16 Ks[64][72];        // [key][d]
  __shared__ bf16 Vs[64][72];        // [d][key]  (from global V^T)
  __shared__ bf16 Ps[4][16][72];     // per-wave P^T as [qrow][key]

  const int bid = blockIdx.x;
  const int qt = bid >> hbits;
  const int hb = bid & ((1 << hbits) - 1);
  const int h  = (hbits == 5) ? (hb >> 1) : hb;
  const int b  = (hbits == 5) ? (hb & 1) : 0;
  const int t = threadIdx.x;
  const int w = t >> 6, lane = t & 63;
  const int q = lane >> 4, i = lane & 15;

  const bf16* Qb = Q  + (size_t)b * (NN * DD) + h * HDD;
  const bf16* Kb = K  + (size_t)b * (LL * DD) + h * HDD;
  const bf16* Vb = Vt + (size_t)b * (DD * (size_t)LL) + (size_t)(h * HDD) * LL;
  const float* biasFb = biasF + b * LL;

  const int qrow = qt * 64 + w * 16;
  bf16x8 qfrag[2];
#pragma unroll
  for (int ks = 0; ks < 2; ks++)
    qfrag[ks] = *(const bf16x8*)&Qb[(size_t)(qrow + i) * DD + ks * 32 + q * 8];

  floatx4 oacc[4];                   // O^T[d = n*16+q*4+r][qrow = i]
#pragma unroll
  for (int n = 0; n < 4; n++) {
#pragma unroll
    for (int r = 0; r < 4; r++) oacc[n][r] = 0.0f;
  }
  float psum = 0.0f;

  const int ldr = t >> 3;          // 0..31
  const int ldc = (t & 7) * 8;     // 0..56

  // preload tile 0 (K/V + bias) into registers
  bf16x8 pk0 = *(const bf16x8*)&Kb[(size_t)ldr * DD + ldc];
  bf16x8 pk1 = *(const bf16x8*)&Kb[(size_t)(ldr + 32) * DD + ldc];
  bf16x8 pv0 = *(const bf16x8*)&Vb[(size_t)ldr * LL + ldc];
  bf16x8 pv1 = *(const bf16x8*)&Vb[(size_t)(ldr + 32) * LL + ldc];
  floatx4 pb[4];
#pragma unroll
  for (int n = 0; n < 4; n++)
    pb[n] = *(const floatx4*)&biasFb[n * 16 + q * 4];

  for (int kt = 0; kt < LL; kt += 64) {
    __syncthreads();
    *(bf16x8*)&Ks[ldr][ldc]      = pk0;
    *(bf16x8*)&Ks[ldr + 32][ldc] = pk1;
    *(bf16x8*)&Vs[ldr][ldc]      = pv0;
    *(bf16x8*)&Vs[ldr + 32][ldc] = pv1;
    __syncthreads();

    // prefetch next K/V tile (wraps on last iter; harmless L2 re-hit)
    {
      const int ktn = (kt + 64) & (LL - 1);
      pk0 = *(const bf16x8*)&Kb[(size_t)(ktn + ldr) * DD + ldc];
      pk1 = *(const bf16x8*)&Kb[(size_t)(ktn + ldr + 32) * DD + ldc];
      pv0 = *(const bf16x8*)&Vb[(size_t)ldr * LL + ktn + ldc];
      pv1 = *(const bf16x8*)&Vb[(size_t)(ldr + 32) * LL + ktn + ldc];
    }

    // S^T[key][qrow] = K·Q^T + maskbias  (contraction over d)
#pragma unroll
    for (int n = 0; n < 4; n++) {
      floatx4 a = pb[n];
#pragma unroll
      for (int ks = 0; ks < 2; ks++) {
        bf16x8 kf = *(const bf16x8*)&Ks[n * 16 + i][ks * 32 + q * 8];
        a = __builtin_amdgcn_mfma_f32_16x16x32_bf16(kf, qfrag[ks], a, 0, 0, 0);
      }
      bf16x4 v4;
#pragma unroll
      for (int r = 0; r < 4; r++) {
        float p = __builtin_amdgcn_exp2f(fminf(a[r], PCLAMP));
        psum += p;
        v4[r] = (bf16)p;
      }
      *(bf16x4*)&Ps[w][i][n * 16 + q * 4] = v4;
    }
    // prefetch next tile's bias (after last pb use)
    {
      const int ktn = (kt + 64) & (LL - 1);
#pragma unroll
      for (int n = 0; n < 4; n++)
        pb[n] = *(const floatx4*)&biasFb[ktn + n * 16 + q * 4];
    }
    // per-wave Ps buffer: DS pipe in-order per wave; no barrier needed
    bf16x8 pf[2];
#pragma unroll
    for (int ks = 0; ks < 2; ks++)
      pf[ks] = *(const bf16x8*)&Ps[w][i][ks * 32 + q * 8];
    // O^T += V^T · P^T  (contraction over key)
#pragma unroll
    for (int n = 0; n < 4; n++) {
#pragma unroll
      for (int ks = 0; ks < 2; ks++) {
        bf16x8 vf = *(const bf16x8*)&Vs[n * 16 + i][ks * 32 + q * 8];
        oacc[n] = __builtin_amdgcn_mfma_f32_16x16x32_bf16(vf, pf[ks], oacc[n], 0, 0, 0);
      }
    }
  }

  psum += __shfl_xor(psum, 16, 64);
  psum += __shfl_xor(psum, 32, 64);
  float inv = 1.0f / fmaxf(psum, 1e-30f);

  bf16* Ob = O + (size_t)b * (NN * DD) + h * HDD;
#pragma unroll
  for (int n = 0; n < 4; n++) {
    bf16x4 v4;
#pragma unroll
    for (int r = 0; r < 4; r++) v4[r] = (bf16)(oacc[n][r] * inv);
    *(bf16x4*)&Ob[(size_t)(qrow + i) * DD + n * 16 + q * 4] = v4;
  }
}

// ---------------------------------------------------------------------------
extern "C" void kernel_launch(void* const* d_in, const int* in_sizes, int n_in,
                              void* d_out, int out_size, void* d_ws, size_t ws_size,
                              hipStream_t stream)
{
  const float* x_q  = (const float*)d_in[0];
  const float* x_kv = (const float*)d_in[1];
  const void*  pad  = d_in[2];
  const float* wq = (const float*)d_in[3];
  const float* bq = (const float*)d_in[4];
  const float* wk = (const float*)d_in[5];
  const float* bk = (const float*)d_in[6];
  const float* wv = (const float*)d_in[7];
  const float* bv = (const float*)d_in[8];
  const float* wo = (const float*)d_in[9];
  const float* bo = (const float*)d_in[10];
  float* out = (float*)d_out;

  char* ws = (char*)d_ws;
  const size_t MB = (size_t)1 << 20;
  const size_t fullElems = (size_t)BB * NN * DD;  // 4M
  const size_t batchElems = (size_t)NN * DD;      // 2M

  if (ws_size >= 49 * MB) {
    bf16* Xqb   = (bf16*)(ws);            // 8 MB, reused as Op after Q-GEMM
    bf16* Xkvb  = (bf16*)(ws + 8 * MB);
    bf16* Wtq   = (bf16*)(ws + 16 * MB);
    bf16* Wtk   = (bf16*)(ws + 18 * MB);
    bf16* Wtv   = (bf16*)(ws + 20 * MB);
    bf16* Wto   = (bf16*)(ws + 22 * MB);
    bf16* Qp    = (bf16*)(ws + 24 * MB);
    bf16* Kp    = (bf16*)(ws + 32 * MB);
    bf16* VtG   = (bf16*)(ws + 40 * MB);
    float* biasF = (float*)(ws + 48 * MB);  // 16 KB
    bf16* Op    = Xqb;

    prep_kernel<<<5121, 256, 0, stream>>>(x_q, x_kv, Xqb, Xkvb, 4096, (int)fullElems,
                                          wq, wk, wv, wo, Wtq, Wtk, Wtv, Wto,
                                          (const unsigned*)pad, biasF);
    qkv_gemm32<<<768, 256, 0, stream>>>(Xqb, Xkvb, Wtq, Wtk, Wtv, bq, bk, bv, Qp, Kp, VtG, 8);
    attn_kernel<<<1024, 256, 0, stream>>>(Qp, Kp, VtG, biasF, Op, 5);
    out_gemm<<<512, 256, 0, stream>>>(Op, Wto, bo, out);
  } else {
    bf16* Wtq   = (bf16*)(ws);
    bf16* Wtk   = (bf16*)(ws + 2 * MB);
    bf16* Wtv   = (bf16*)(ws + 4 * MB);
    bf16* Wto   = (bf16*)(ws + 6 * MB);
    bf16* Xqb   = (bf16*)(ws + 8 * MB);   // 4 MB, reused as Op
    bf16* Xkvb  = (bf16*)(ws + 12 * MB);
    bf16* Qp    = (bf16*)(ws + 16 * MB);
    bf16* Kp    = (bf16*)(ws + 20 * MB);
    bf16* VtG   = (bf16*)(ws + 24 * MB);
    float* biasF = (float*)(ws + 28 * MB);
    bf16* Op    = Xqb;

    for (int b = 0; b < BB; b++) {
      if (b == 0)
        prep_kernel<<<3073, 256, 0, stream>>>(x_q, x_kv, Xqb, Xkvb, 2048, (int)batchElems,
                                              wq, wk, wv, wo, Wtq, Wtk, Wtv, Wto,
                                              (const unsigned*)pad, biasF);
      else
        prep_kernel<<<2048, 256, 0, stream>>>(x_q + b * batchElems, x_kv + b * batchElems,
                                              Xqb, Xkvb, 2048, (int)batchElems,
                                              wq, wk, wv, wo, Wtq, Wtk, Wtv, Wto,
                                              (const unsigned*)pad, biasF);
      qkv_gemm32<<<384, 256, 0, stream>>>(Xqb, Xkvb, Wtq, Wtk, Wtv, bq, bk, bv, Qp, Kp, VtG, 7);
      attn_kernel<<<512, 256, 0, stream>>>(Qp, Kp, VtG, biasF + b * LL, Op, 4);
      out_gemm<<<256, 256, 0, stream>>>(Op, Wto, bo, out + b * batchElems);
    }
  }
}

// Round 11
// 236.439 us; speedup vs baseline: 1.1315x; 1.1315x over previous
//
#include <hip/hip_runtime.h>
#include <hip/hip_bf16.h>
#include <math.h>

typedef __bf16 bf16;
typedef __attribute__((ext_vector_type(8))) __bf16 bf16x8;
typedef __attribute__((ext_vector_type(4))) __bf16 bf16x4;
typedef __attribute__((ext_vector_type(4))) float floatx4;
typedef __attribute__((ext_vector_type(16))) float floatx16;

#define BB 2
#define NN 2048
#define LL 2048
#define DD 1024
#define HH 16
#define HDD 64

// Q pre-scale: HD^-0.5 * log2(e) -> scores in log2 units
#define QSCALE (0.125f * 1.44269504f)
#define PCLAMP 21.66f
#define MBIAS  (-100000.0f)

// async global->LDS, 16B per lane. LDS dest must be wave-uniform + lane*16.
__device__ __forceinline__ void async16(const bf16* g, bf16* l) {
  __builtin_amdgcn_global_load_lds((const __attribute__((address_space(1))) void*)(g),
                                   (__attribute__((address_space(3))) void*)(l), 16, 0, 0);
}

// ---------------------------------------------------------------------------
// Fused prep: [0,nconv) f32->bf16 converts (two inputs, nconv/2 blocks each),
// [nconv, nconv+1024) W-transpose tiles (4 matrices), [nconv+1024] mask ->
// biasF floats (dtype auto-detect: int32 {0,1} / bytes / f32 {0,1}).
// ---------------------------------------------------------------------------
__global__ __launch_bounds__(256) void prep_kernel(
    const float* __restrict__ xq, const float* __restrict__ xkv,
    bf16* __restrict__ Xqb, bf16* __restrict__ Xkvb, int nconv, int elemsEach,
    const float* __restrict__ W0, const float* __restrict__ W1,
    const float* __restrict__ W2, const float* __restrict__ W3,
    bf16* __restrict__ T0, bf16* __restrict__ T1,
    bf16* __restrict__ T2, bf16* __restrict__ T3,
    const unsigned* __restrict__ mask, float* __restrict__ biasF)
{
  __shared__ bf16 Tb[64][72];
  const int bid = blockIdx.x;
  const int t = threadIdx.x;

  if (bid < nconv) {
    const int half = nconv >> 1;
    const float* s = (bid < half) ? xq : xkv;
    bf16* d = (bid < half) ? Xqb : Xkvb;
    int gid = (bid < half) ? bid : bid - half;
    int idx = (gid * 256 + t) * 8;
    if (idx >= elemsEach) return;
    floatx4 a = *(const floatx4*)&s[idx];
    floatx4 b = *(const floatx4*)&s[idx + 4];
    bf16x8 o;
#pragma unroll
    for (int e = 0; e < 4; e++) { o[e] = (bf16)a[e]; o[4 + e] = (bf16)b[e]; }
    *(bf16x8*)&d[idx] = o;
    return;
  }
  if (bid < nconv + 1024) {
    const int wb = bid - nconv;
    const int which = wb >> 8;
    const float* W = which == 0 ? W0 : which == 1 ? W1 : which == 2 ? W2 : W3;
    bf16*       T = which == 0 ? T0 : which == 1 ? T1 : which == 2 ? T2 : T3;
    const int tile = wb & 255;
    const int k0 = (tile >> 4) * 64, n0 = (tile & 15) * 64;
    const int r = t >> 2;
    const int c = (t & 3) * 16;
    const float* Wr = W + (size_t)(k0 + r) * 1024 + n0 + c;
    floatx4 f0 = *(const floatx4*)(Wr + 0);
    floatx4 f1 = *(const floatx4*)(Wr + 4);
    floatx4 f2 = *(const floatx4*)(Wr + 8);
    floatx4 f3 = *(const floatx4*)(Wr + 12);
#pragma unroll
    for (int e = 0; e < 4; e++) {
      Tb[c + e][r]      = (bf16)f0[e];
      Tb[c + 4 + e][r]  = (bf16)f1[e];
      Tb[c + 8 + e][r]  = (bf16)f2[e];
      Tb[c + 12 + e][r] = (bf16)f3[e];
    }
    __syncthreads();
    bf16* Tr = T + (size_t)(n0 + r) * 1024 + k0 + c;
    *(bf16x8*)&Tr[0] = *(const bf16x8*)&Tb[r][c];
    *(bf16x8*)&Tr[8] = *(const bf16x8*)&Tb[r][c + 8];
    return;
  }
  // mask -> biasF (one block)
  __shared__ int hasBig, hasFloat;
  if (t == 0) { hasBig = 0; hasFloat = 0; }
  __syncthreads();
  int big = 0, flt = 0;
  for (int idx = t; idx < 1024; idx += 256) {
    unsigned v = mask[idx];
    if (v == 0x3F800000u) flt = 1;
    else if (v > 1u) big = 1;
  }
  if (big) atomicOr(&hasBig, 1);
  if (flt) atomicOr(&hasFloat, 1);
  __syncthreads();
  const int mode = hasFloat ? 2 : (hasBig ? 1 : 0);
  for (int k = t * 16; k < t * 16 + 16; k++) {
    bool m;
    if (mode == 0)      m = ((const int*)mask)[k] != 0;
    else if (mode == 1) m = ((const unsigned char*)mask)[k] != 0;
    else                m = ((const float*)mask)[k] != 0.0f;
    biasF[k] = m ? MBIAS : 0.0f;
  }
}

// ---------------------------------------------------------------------------
// qkv GEMM body: 128x128 tile, BK=64, 32x32x16 MFMAs, XOR-swizzled LDS.
// Rows are 64 elems (128 B, unpadded -> global_load_lds OK). 16B chunk c of
// row r lives at slot c^(r&7): staging picks the swizzled GLOBAL chunk per
// lane (LDS dest stays base+lane*16); fragment reads de-swizzle. This puts
// every wave b128 at the 8-cycle structural floor (was 32-way conflicted).
// transv: write bf16 V^T globally as Vt[b][col][key].
// ---------------------------------------------------------------------------
template <typename TC>
__device__ __forceinline__ void gemm_body32(
    int bx, const bf16* __restrict__ A, const bf16* __restrict__ Wt,
    const float* __restrict__ bias, TC* __restrict__ C, float scale, int transv)
{
  __shared__ bf16 As[128 * 64];
  __shared__ bf16 Bs[128 * 64];

  const int tm = bx >> 3, tn = bx & 7;
  const int m0 = tm * 128, n0 = tn * 128;
  const int t = threadIdx.x;
  const int w = t >> 6, l = t & 63;
  const int col = l & 31, half = l >> 5;
  const int wm = (w >> 1) * 64, wn = (w & 1) * 64;
  const int sr  = t >> 3;                        // 0..31 (row)
  const int scl = (t & 7) * 8;                   // LDS slot chunk (linear)
  const int scs = (((t & 7) ^ (sr & 7)) * 8);    // swizzled global chunk
  const int csw = col & 7;                       // frag de-swizzle key

  floatx16 acc[2][2];
#pragma unroll
  for (int mi = 0; mi < 2; mi++)
#pragma unroll
    for (int ni = 0; ni < 2; ni++)
#pragma unroll
      for (int e = 0; e < 16; e++) acc[mi][ni][e] = 0.0f;

  for (int k0 = 0; k0 < 1024; k0 += 64) {
    __syncthreads();
#pragma unroll
    for (int j = 0; j < 4; j++)
      async16(&A[(size_t)(m0 + j * 32 + sr) * 1024 + k0 + scs], &As[(j * 32 + sr) * 64 + scl]);
#pragma unroll
    for (int j = 0; j < 4; j++)
      async16(&Wt[(size_t)(n0 + j * 32 + sr) * 1024 + k0 + scs], &Bs[(j * 32 + sr) * 64 + scl]);
    __syncthreads();
#pragma unroll
    for (int kk = 0; kk < 4; kk++) {
      const int ch = ((kk * 2 + half) ^ csw) * 8;  // de-swizzled chunk offset
      bf16x8 af[2], bfr[2];
#pragma unroll
      for (int mi = 0; mi < 2; mi++)
        af[mi] = *(const bf16x8*)&As[(wm + mi * 32 + col) * 64 + ch];
#pragma unroll
      for (int ni = 0; ni < 2; ni++)
        bfr[ni] = *(const bf16x8*)&Bs[(wn + ni * 32 + col) * 64 + ch];
#pragma unroll
      for (int mi = 0; mi < 2; mi++)
#pragma unroll
        for (int ni = 0; ni < 2; ni++)
          acc[mi][ni] = __builtin_amdgcn_mfma_f32_32x32x16_bf16(af[mi], bfr[ni], acc[mi][ni], 0, 0, 0);
    }
  }
  // 32x32 C/D layout: col = lane&31, row = (reg&3) + 8*(reg>>2) + 4*(lane>>5)
#pragma unroll
  for (int ni = 0; ni < 2; ni++) {
    int colg = n0 + wn + ni * 32 + col;
    float bv = bias[colg];
#pragma unroll
    for (int mi = 0; mi < 2; mi++) {
      int rbase = m0 + wm + mi * 32 + half * 4;
      if (transv) {
#pragma unroll
        for (int g = 0; g < 4; g++) {
          int key0 = rbase + g * 8;
          int bb = key0 >> 11, key = key0 & 2047;
          bf16x4 v4;
#pragma unroll
          for (int r = 0; r < 4; r++) v4[r] = (bf16)(acc[mi][ni][g * 4 + r] + bv);
          *(bf16x4*)&((bf16*)C)[(size_t)bb * (DD * (size_t)LL) + (size_t)colg * LL + key] = v4;
        }
      } else {
#pragma unroll
        for (int g = 0; g < 4; g++)
#pragma unroll
          for (int r = 0; r < 4; r++)
            C[(size_t)(rbase + g * 8 + r) * 1024 + colg] = (TC)((acc[mi][ni][g * 4 + r] + bv) * scale);
      }
    }
  }
}

// Fused Q/K/V projection: grid = 3 << shift; which = bid >> shift.
__global__ __launch_bounds__(256) void qkv_gemm32(
    const bf16* __restrict__ Xq, const bf16* __restrict__ Xkv,
    const bf16* __restrict__ Wtq, const bf16* __restrict__ Wtk, const bf16* __restrict__ Wtv,
    const float* __restrict__ bq, const float* __restrict__ bk, const float* __restrict__ bv,
    bf16* __restrict__ Qp, bf16* __restrict__ Kp, bf16* __restrict__ VtG, int shift)
{
  const int bid = blockIdx.x;
  const int which = bid >> shift;
  const int bx = bid & ((1 << shift) - 1);
  if (which == 0)      gemm_body32<bf16>(bx, Xq,  Wtq, bq, Qp,  QSCALE, 0);
  else if (which == 1) gemm_body32<bf16>(bx, Xkv, Wtk, bk, Kp,  1.0f,   0);
  else                 gemm_body32<bf16>(bx, Xkv, Wtv, bv, VtG, 1.0f,   1);
}

// ---------------------------------------------------------------------------
// out GEMM: 128x64 tile, BK=64, 16x16x32 MFMAs, XOR-swizzled LDS (same
// scheme: chunk c of row r at slot c^(r&7)).
// ---------------------------------------------------------------------------
__global__ __launch_bounds__(256) void out_gemm(
    const bf16* __restrict__ A, const bf16* __restrict__ Wt,
    const float* __restrict__ bias, float* __restrict__ C)
{
  __shared__ bf16 As[128 * 64];
  __shared__ bf16 Bs[64 * 64];

  const int bx = blockIdx.x;
  const int tm = bx >> 4, tn = bx & 15;
  const int m0 = tm * 128, n0 = tn * 64;
  const int t = threadIdx.x;
  const int w = t >> 6, l = t & 63;
  const int q = l >> 4, i = l & 15;
  const int wm = (w >> 1) * 64, wn = (w & 1) * 32;
  const int sr  = t >> 3;
  const int scl = (t & 7) * 8;
  const int scs = (((t & 7) ^ (sr & 7)) * 8);
  const int isw = i & 7;

  const floatx4 zero = {0.f, 0.f, 0.f, 0.f};
  floatx4 acc[4][2];
#pragma unroll
  for (int mi = 0; mi < 4; mi++)
#pragma unroll
    for (int ni = 0; ni < 2; ni++) acc[mi][ni] = zero;

  for (int k0 = 0; k0 < 1024; k0 += 64) {
    __syncthreads();
#pragma unroll
    for (int j = 0; j < 4; j++)
      async16(&A[(size_t)(m0 + j * 32 + sr) * 1024 + k0 + scs], &As[(j * 32 + sr) * 64 + scl]);
#pragma unroll
    for (int j = 0; j < 2; j++)
      async16(&Wt[(size_t)(n0 + j * 32 + sr) * 1024 + k0 + scs], &Bs[(j * 32 + sr) * 64 + scl]);
    __syncthreads();
#pragma unroll
    for (int ks = 0; ks < 2; ks++) {
#pragma unroll
      for (int qq = 0; qq < 1; qq++) {}  // (keep structure flat)
      const int ch = ((ks * 4 + q) ^ isw) * 8;
      bf16x8 af[4], bfr[2];
#pragma unroll
      for (int mi = 0; mi < 4; mi++)
        af[mi] = *(const bf16x8*)&As[(wm + mi * 16 + i) * 64 + ch];
#pragma unroll
      for (int ni = 0; ni < 2; ni++)
        bfr[ni] = *(const bf16x8*)&Bs[(wn + ni * 16 + i) * 64 + ch];
#pragma unroll
      for (int mi = 0; mi < 4; mi++)
#pragma unroll
        for (int ni = 0; ni < 2; ni++)
          acc[mi][ni] = __builtin_amdgcn_mfma_f32_16x16x32_bf16(af[mi], bfr[ni], acc[mi][ni], 0, 0, 0);
    }
  }
#pragma unroll
  for (int ni = 0; ni < 2; ni++) {
    int colg = n0 + wn + ni * 16 + i;
    float bv = bias[colg];
#pragma unroll
    for (int mi = 0; mi < 4; mi++) {
      int row = m0 + wm + mi * 16 + q * 4;
#pragma unroll
      for (int r = 0; r < 4; r++)
        C[(size_t)(row + r) * 1024 + colg] = acc[mi][ni][r] + bv;
    }
  }
}

// ---------------------------------------------------------------------------
// Flash attention (round-9 proven, 82 us): block = 64 qrows, 4 waves x 16
// qrows; XCD swizzle; register double-buffered K/V + bias; S^T formulation;
// fixed-max softmax in log2 units; padded LDS (manual staging) so fragment
// reads are already at the bank floor.
// ---------------------------------------------------------------------------
__global__ __launch_bounds__(256) void attn_kernel(
    const bf16* __restrict__ Q, const bf16* __restrict__ K,
    const bf16* __restrict__ Vt, const float* __restrict__ biasF,
    bf16* __restrict__ O, int hbits)
{
  __shared__ bf16 Ks[64][72];        // [key][d]
  __shared__ bf16 Vs[64][72];        // [d][key]  (from global V^T)
  __shared__ bf16 Ps[4][16][72];     // per-wave P^T as [qrow][key]

  const int bid = blockIdx.x;
  const int qt = bid >> hbits;
  const int hb = bid & ((1 << hbits) - 1);
  const int h  = (hbits == 5) ? (hb >> 1) : hb;
  const int b  = (hbits == 5) ? (hb & 1) : 0;
  const int t = threadIdx.x;
  const int w = t >> 6, lane = t & 63;
  const int q = lane >> 4, i = lane & 15;

  const bf16* Qb = Q  + (size_t)b * (NN * DD) + h * HDD;
  const bf16* Kb = K  + (size_t)b * (LL * DD) + h * HDD;
  const bf16* Vb = Vt + (size_t)b * (DD * (size_t)LL) + (size_t)(h * HDD) * LL;
  const float* biasFb = biasF + b * LL;

  const int qrow = qt * 64 + w * 16;
  bf16x8 qfrag[2];
#pragma unroll
  for (int ks = 0; ks < 2; ks++)
    qfrag[ks] = *(const bf16x8*)&Qb[(size_t)(qrow + i) * DD + ks * 32 + q * 8];

  floatx4 oacc[4];                   // O^T[d = n*16+q*4+r][qrow = i]
#pragma unroll
  for (int n = 0; n < 4; n++) {
#pragma unroll
    for (int r = 0; r < 4; r++) oacc[n][r] = 0.0f;
  }
  float psum = 0.0f;

  const int ldr = t >> 3;          // 0..31
  const int ldc = (t & 7) * 8;     // 0..56

  // preload tile 0 (K/V + bias) into registers
  bf16x8 pk0 = *(const bf16x8*)&Kb[(size_t)ldr * DD + ldc];
  bf16x8 pk1 = *(const bf16x8*)&Kb[(size_t)(ldr + 32) * DD + ldc];
  bf16x8 pv0 = *(const bf16x8*)&Vb[(size_t)ldr * LL + ldc];
  bf16x8 pv1 = *(const bf16x8*)&Vb[(size_t)(ldr + 32) * LL + ldc];
  floatx4 pb[4];
#pragma unroll
  for (int n = 0; n < 4; n++)
    pb[n] = *(const floatx4*)&biasFb[n * 16 + q * 4];

  for (int kt = 0; kt < LL; kt += 64) {
    __syncthreads();
    *(bf16x8*)&Ks[ldr][ldc]      = pk0;
    *(bf16x8*)&Ks[ldr + 32][ldc] = pk1;
    *(bf16x8*)&Vs[ldr][ldc]      = pv0;
    *(bf16x8*)&Vs[ldr + 32][ldc] = pv1;
    __syncthreads();

    // prefetch next K/V tile (wraps on last iter; harmless L2 re-hit)
    {
      const int ktn = (kt + 64) & (LL - 1);
      pk0 = *(const bf16x8*)&Kb[(size_t)(ktn + ldr) * DD + ldc];
      pk1 = *(const bf16x8*)&Kb[(size_t)(ktn + ldr + 32) * DD + ldc];
      pv0 = *(const bf16x8*)&Vb[(size_t)ldr * LL + ktn + ldc];
      pv1 = *(const bf16x8*)&Vb[(size_t)(ldr + 32) * LL + ktn + ldc];
    }

    // S^T[key][qrow] = K·Q^T + maskbias  (contraction over d)
#pragma unroll
    for (int n = 0; n < 4; n++) {
      floatx4 a = pb[n];
#pragma unroll
      for (int ks = 0; ks < 2; ks++) {
        bf16x8 kf = *(const bf16x8*)&Ks[n * 16 + i][ks * 32 + q * 8];
        a = __builtin_amdgcn_mfma_f32_16x16x32_bf16(kf, qfrag[ks], a, 0, 0, 0);
      }
      bf16x4 v4;
#pragma unroll
      for (int r = 0; r < 4; r++) {
        float p = __builtin_amdgcn_exp2f(fminf(a[r], PCLAMP));
        psum += p;
        v4[r] = (bf16)p;
      }
      *(bf16x4*)&Ps[w][i][n * 16 + q * 4] = v4;
    }
    // prefetch next tile's bias (after last pb use)
    {
      const int ktn = (kt + 64) & (LL - 1);
#pragma unroll
      for (int n = 0; n < 4; n++)
        pb[n] = *(const floatx4*)&biasFb[ktn + n * 16 + q * 4];
    }
    // per-wave Ps buffer: DS pipe in-order per wave; no barrier needed
    bf16x8 pf[2];
#pragma unroll
    for (int ks = 0; ks < 2; ks++)
      pf[ks] = *(const bf16x8*)&Ps[w][i][ks * 32 + q * 8];
    // O^T += V^T · P^T  (contraction over key)
#pragma unroll
    for (int n = 0; n < 4; n++) {
#pragma unroll
      for (int ks = 0; ks < 2; ks++) {
        bf16x8 vf = *(const bf16x8*)&Vs[n * 16 + i][ks * 32 + q * 8];
        oacc[n] = __builtin_amdgcn_mfma_f32_16x16x32_bf16(vf, pf[ks], oacc[n], 0, 0, 0);
      }
    }
  }

  psum += __shfl_xor(psum, 16, 64);
  psum += __shfl_xor(psum, 32, 64);
  float inv = 1.0f / fmaxf(psum, 1e-30f);

  bf16* Ob = O + (size_t)b * (NN * DD) + h * HDD;
#pragma unroll
  for (int n = 0; n < 4; n++) {
    bf16x4 v4;
#pragma unroll
    for (int r = 0; r < 4; r++) v4[r] = (bf16)(oacc[n][r] * inv);
    *(bf16x4*)&Ob[(size_t)(qrow + i) * DD + n * 16 + q * 4] = v4;
  }
}

// ---------------------------------------------------------------------------
extern "C" void kernel_launch(void* const* d_in, const int* in_sizes, int n_in,
                              void* d_out, int out_size, void* d_ws, size_t ws_size,
                              hipStream_t stream)
{
  const float* x_q  = (const float*)d_in[0];
  const float* x_kv = (const float*)d_in[1];
  const void*  pad  = d_in[2];
  const float* wq = (const float*)d_in[3];
  const float* bq = (const float*)d_in[4];
  const float* wk = (const float*)d_in[5];
  const float* bk = (const float*)d_in[6];
  const float* wv = (const float*)d_in[7];
  const float* bv = (const float*)d_in[8];
  const float* wo = (const float*)d_in[9];
  const float* bo = (const float*)d_in[10];
  float* out = (float*)d_out;

  char* ws = (char*)d_ws;
  const size_t MB = (size_t)1 << 20;
  const size_t fullElems = (size_t)BB * NN * DD;  // 4M
  const size_t batchElems = (size_t)NN * DD;      // 2M

  if (ws_size >= 49 * MB) {
    bf16* Xqb   = (bf16*)(ws);            // 8 MB, reused as Op after Q-GEMM
    bf16* Xkvb  = (bf16*)(ws + 8 * MB);
    bf16* Wtq   = (bf16*)(ws + 16 * MB);
    bf16* Wtk   = (bf16*)(ws + 18 * MB);
    bf16* Wtv   = (bf16*)(ws + 20 * MB);
    bf16* Wto   = (bf16*)(ws + 22 * MB);
    bf16* Qp    = (bf16*)(ws + 24 * MB);
    bf16* Kp    = (bf16*)(ws + 32 * MB);
    bf16* VtG   = (bf16*)(ws + 40 * MB);
    float* biasF = (float*)(ws + 48 * MB);  // 16 KB
    bf16* Op    = Xqb;

    prep_kernel<<<5121, 256, 0, stream>>>(x_q, x_kv, Xqb, Xkvb, 4096, (int)fullElems,
                                          wq, wk, wv, wo, Wtq, Wtk, Wtv, Wto,
                                          (const unsigned*)pad, biasF);
    qkv_gemm32<<<768, 256, 0, stream>>>(Xqb, Xkvb, Wtq, Wtk, Wtv, bq, bk, bv, Qp, Kp, VtG, 8);
    attn_kernel<<<1024, 256, 0, stream>>>(Qp, Kp, VtG, biasF, Op, 5);
    out_gemm<<<512, 256, 0, stream>>>(Op, Wto, bo, out);
  } else {
    bf16* Wtq   = (bf16*)(ws);
    bf16* Wtk   = (bf16*)(ws + 2 * MB);
    bf16* Wtv   = (bf16*)(ws + 4 * MB);
    bf16* Wto   = (bf16*)(ws + 6 * MB);
    bf16* Xqb   = (bf16*)(ws + 8 * MB);   // 4 MB, reused as Op
    bf16* Xkvb  = (bf16*)(ws + 12 * MB);
    bf16* Qp    = (bf16*)(ws + 16 * MB);
    bf16* Kp    = (bf16*)(ws + 20 * MB);
    bf16* VtG   = (bf16*)(ws + 24 * MB);
    float* biasF = (float*)(ws + 28 * MB);
    bf16* Op    = Xqb;

    for (int b = 0; b < BB; b++) {
      if (b == 0)
        prep_kernel<<<3073, 256, 0, stream>>>(x_q, x_kv, Xqb, Xkvb, 2048, (int)batchElems,
                                              wq, wk, wv, wo, Wtq, Wtk, Wtv, Wto,
                                              (const unsigned*)pad, biasF);
      else
        prep_kernel<<<2048, 256, 0, stream>>>(x_q + b * batchElems, x_kv + b * batchElems,
                                              Xqb, Xkvb, 2048, (int)batchElems,
                                              wq, wk, wv, wo, Wtq, Wtk, Wtv, Wto,
                                              (const unsigned*)pad, biasF);
      qkv_gemm32<<<384, 256, 0, stream>>>(Xqb, Xkvb, Wtq, Wtk, Wtv, bq, bk, bv, Qp, Kp, VtG, 7);
      attn_kernel<<<512, 256, 0, stream>>>(Qp, Kp, VtG, biasF + b * LL, Op, 4);
      out_gemm<<<256, 256, 0, stream>>>(Op, Wto, bo, out + b * batchElems);
    }
  }
}